// Round 16
// baseline (136.633 us; speedup 1.0000x reference)
//
#include <hip/hip_runtime.h>

// GCN layer: out = scatter_add(rows, vals[:,None] * embeds[cols]) over COO.
// N=50000, E=800000, D=96 (fp32 in/out; indices int32 per harness).
//
// R13: fused sort+accumulate + premultiplied col*96: 65.2us.
// R14: EPB 1024 FAILED (uncoalesced (bin,block)-matrix traffic x4).
// R15: R13 + 512-thread hist/scatter blocks (TLP, zero extra traffic): 59.6us.
// R16: decoupled scan — last-finishing scan block does the level-2 bsums scan
//      (threadfence + device atomic counter; counter zeroed by hist which
//      precedes in stream order). Removes the scan_sums dispatch + gap.

#define DFEAT    96
#define BINSHIFT 5
#define BINROWS  32            // rows per bin
#define MAXBIN   2048          // LDS hist/cursor capacity (8KB)
#define EPB      4096          // edges per hist/scatter block
#define SCT      1024          // scan width
#define CAP      1024          // edges per sortaccum chunk (8KB LDS)

__device__ inline unsigned bf16_rne(float x) {
    unsigned u = __float_as_uint(x);
    return (u + 0x7FFFu + ((u >> 16) & 1u)) >> 16;
}
__device__ inline float bf16_to_f32(unsigned short u) {
    return __uint_as_float((unsigned)u << 16);
}

// Blocks [0,B): LDS histogram of this block's EPB edges over nbin bins,
//   written to matrix[bin*B + block] (bin-major for the flat scan).
// Blocks [B,...): fp32 -> bf16 embeds compression (8 floats/thread, row-major).
// Block 0 thread 0 also zeroes the decoupled-scan completion counter.
// Launched with 512 threads (8 waves/block) for latency hiding.
__global__ void hist_bin_compress_kernel(const int* __restrict__ rows,
                                         int* __restrict__ matrix, int E, int B, int nbin,
                                         const float* __restrict__ embeds,
                                         unsigned short* __restrict__ ebf, int nOct,
                                         int* __restrict__ counter) {
    __shared__ int cnt[MAXBIN];
    int b = blockIdx.x;
    if (b == 0 && threadIdx.x == 0) *counter = 0;
    if (b < B) {
        for (int k = threadIdx.x; k < nbin; k += blockDim.x) cnt[k] = 0;
        __syncthreads();
        int base = b * EPB;
        int lim  = min(base + EPB, E);
        for (int i = base + threadIdx.x; i < lim; i += blockDim.x)
            atomicAdd(&cnt[rows[i] >> BINSHIFT], 1);
        __syncthreads();
        for (int k = threadIdx.x; k < nbin; k += blockDim.x)
            matrix[(size_t)k * B + b] = cnt[k];
    } else {
        int j = (b - B) * blockDim.x + threadIdx.x;
        if (j < nOct) {
            const float4* src = reinterpret_cast<const float4*>(embeds) + (size_t)j * 2;
            float4 f0 = src[0];
            float4 f1 = src[1];
            uint4 o;
            o.x = bf16_rne(f0.x) | (bf16_rne(f0.y) << 16);
            o.y = bf16_rne(f0.z) | (bf16_rne(f0.w) << 16);
            o.z = bf16_rne(f1.x) | (bf16_rne(f1.y) << 16);
            o.w = bf16_rne(f1.z) | (bf16_rne(f1.w) << 16);
            reinterpret_cast<uint4*>(ebf)[j] = o;
        }
    }
}

// In-place per-block exclusive scan (one elem/thread, coalesced); block sums
// out. The LAST block to finish (device atomic counter) exclusive-scans the
// block sums in place — no separate level-2 dispatch. Result stays partial:
// consumers add bsums[flatIdx >> 10].
__global__ void scan1024_dc_kernel(int* __restrict__ data, int* __restrict__ bsums,
                                   int* __restrict__ counter, int n, int nblocks) {
    __shared__ int s[SCT];
    __shared__ int amLast;
    int t = threadIdx.x;
    int i = blockIdx.x * SCT + t;
    int v = (i < n) ? data[i] : 0;
    s[t] = v;
    __syncthreads();
    for (int off = 1; off < SCT; off <<= 1) {
        int u = (t >= off) ? s[t - off] : 0;
        __syncthreads();
        s[t] += u;
        __syncthreads();
    }
    if (i < n) data[i] = s[t] - v;
    if (t == SCT - 1) bsums[blockIdx.x] = s[t];

    // Decoupled level-2: last finisher scans bsums.
    __threadfence();                       // release our bsums write
    if (t == 0) amLast = (atomicAdd(counter, 1) == nblocks - 1);
    __syncthreads();
    if (amLast) {
        __threadfence();                   // acquire others' bsums writes
        int w = (t < nblocks) ? bsums[t] : 0;
        __syncthreads();                   // s[] reuse barrier
        s[t] = w;
        __syncthreads();
        for (int off = 1; off < SCT; off <<= 1) {
            int u = (t >= off) ? s[t - off] : 0;
            __syncthreads();
            s[t] += u;
            __syncthreads();
        }
        if (t < nblocks) bsums[t] = s[t] - w;
    }
}

__device__ inline int scanned_at(const int* __restrict__ matrixScan,
                                 const int* __restrict__ bsums, long long flatIdx) {
    return matrixScan[flatIdx] + bsums[flatIdx >> 10];
}

// Scatter edges to row-bin buckets. Cursor bases from the scanned matrix
// (+bsums fixup); within-block ranks via LDS atomics only.
// entry: (lrow<<16 | col, val) with lrow in [0,32), col < 65536.
// Launched with 512 threads (8 waves/block) for latency hiding.
__global__ void scatter_bin_kernel(const int* __restrict__ rows, const int* __restrict__ cols,
                                   const float* __restrict__ vals,
                                   const int* __restrict__ matrixScan,
                                   const int* __restrict__ bsums,
                                   int2* __restrict__ bucket, int E, int B, int nbin) {
    __shared__ int cur[MAXBIN];
    int b = blockIdx.x;
    for (int k = threadIdx.x; k < nbin; k += blockDim.x)
        cur[k] = scanned_at(matrixScan, bsums, (long long)k * B + b);
    __syncthreads();
    int base = b * EPB;
    int lim  = min(base + EPB, E);
    for (int i = base + threadIdx.x; i < lim; i += blockDim.x) {
        int r = rows[i];
        int bin = r >> BINSHIFT;
        int pos = atomicAdd(&cur[bin], 1);
        bucket[pos] = make_int2(((r & (BINROWS - 1)) << 16) | cols[i],
                                __float_as_int(vals[i]));
    }
}

// One 256-thread block per 32-row bin. Per 1024-edge chunk: edges -> registers
// (coalesced), LDS count over 32 row-counters, 32-wide LDS scan, cursor-scatter
// into sorted LDS (stores PREMULTIPLIED col*96 — lrow implicit in segments);
// then each half-wave accumulates its 4 rows from LDS (broadcast reads) with
// register accumulators persisting across chunks. Single feature pass.
__global__ void sortaccum_kernel(const int2* __restrict__ bucket,
                                 const int* __restrict__ matrixScan,
                                 const int* __restrict__ bsums,
                                 const unsigned short* __restrict__ ebf,
                                 float* __restrict__ out, int E, int B, int nbin, int N) {
    __shared__ int2 sorted[CAP];     // 8 KB
    __shared__ int cnt[BINROWS];
    __shared__ int segs[BINROWS];
    __shared__ int cur[BINROWS];
    __shared__ int s32[BINROWS];

    int bin = blockIdx.x;
    int t = threadIdx.x;
    int hw = t >> 5;                 // 8 half-waves
    int lane = t & 31;

    int start = scanned_at(matrixScan, bsums, (long long)bin * B);
    int end   = (bin + 1 < nbin) ? scanned_at(matrixScan, bsums, (long long)(bin + 1) * B) : E;

    float acc[4][3];
    #pragma unroll
    for (int rr = 0; rr < 4; ++rr) { acc[rr][0] = 0.f; acc[rr][1] = 0.f; acc[rr][2] = 0.f; }

    for (int cs = start; cs < end; cs += CAP) {
        int m = min(CAP, end - cs);

        if (t < BINROWS) cnt[t] = 0;
        __syncthreads();

        // Load chunk edges into registers + LDS count.
        int2 ee[4];
        #pragma unroll
        for (int k = 0; k < 4; ++k) {
            int j = t + k * 256;
            if (j < m) {
                ee[k] = bucket[cs + j];
                atomicAdd(&cnt[ee[k].x >> 16], 1);
            }
        }
        __syncthreads();

        // Exclusive scan of the 32 counters.
        if (t < BINROWS) s32[t] = cnt[t];
        __syncthreads();
        for (int off = 1; off < BINROWS; off <<= 1) {
            int u = (t < BINROWS && t >= off) ? s32[t - off] : 0;
            __syncthreads();
            if (t < BINROWS) s32[t] += u;
            __syncthreads();
        }
        if (t < BINROWS) {
            int ex = s32[t] - cnt[t];
            segs[t] = ex;
            cur[t]  = ex;
        }
        __syncthreads();

        // Cursor-scatter into sorted LDS; store premultiplied row offset col*96.
        #pragma unroll
        for (int k = 0; k < 4; ++k) {
            int j = t + k * 256;
            if (j < m) {
                int pos = atomicAdd(&cur[ee[k].x >> 16], 1);
                sorted[pos] = make_int2((ee[k].x & 0xFFFF) * DFEAT, ee[k].y);
            }
        }
        __syncthreads();

        // Accumulate: half-wave hw owns rows hw*4 .. hw*4+3.
        #pragma unroll
        for (int rr = 0; rr < 4; ++rr) {
            int r = hw * 4 + rr;
            int j  = segs[r];
            int je = segs[r] + cnt[r];
            for (; j + 4 <= je; j += 4) {
                int2 p0 = sorted[j];
                int2 p1 = sorted[j + 1];
                int2 p2 = sorted[j + 2];
                int2 p3 = sorted[j + 3];
                float v0 = __int_as_float(p0.y), v1 = __int_as_float(p1.y);
                float v2 = __int_as_float(p2.y), v3 = __int_as_float(p3.y);
                float x0 = bf16_to_f32(ebf[p0.x + lane]);
                float y0 = bf16_to_f32(ebf[p0.x + lane + 32]);
                float z0 = bf16_to_f32(ebf[p0.x + lane + 64]);
                float x1 = bf16_to_f32(ebf[p1.x + lane]);
                float y1 = bf16_to_f32(ebf[p1.x + lane + 32]);
                float z1 = bf16_to_f32(ebf[p1.x + lane + 64]);
                float x2 = bf16_to_f32(ebf[p2.x + lane]);
                float y2 = bf16_to_f32(ebf[p2.x + lane + 32]);
                float z2 = bf16_to_f32(ebf[p2.x + lane + 64]);
                float x3 = bf16_to_f32(ebf[p3.x + lane]);
                float y3 = bf16_to_f32(ebf[p3.x + lane + 32]);
                float z3 = bf16_to_f32(ebf[p3.x + lane + 64]);
                acc[rr][0] += v0 * x0 + v1 * x1;
                acc[rr][1] += v0 * y0 + v1 * y1;
                acc[rr][2] += v0 * z0 + v1 * z1;
                acc[rr][0] += v2 * x2 + v3 * x3;
                acc[rr][1] += v2 * y2 + v3 * y3;
                acc[rr][2] += v2 * z2 + v3 * z3;
            }
            for (; j < je; ++j) {
                int2 p = sorted[j];
                float v = __int_as_float(p.y);
                acc[rr][0] += v * bf16_to_f32(ebf[p.x + lane]);
                acc[rr][1] += v * bf16_to_f32(ebf[p.x + lane + 32]);
                acc[rr][2] += v * bf16_to_f32(ebf[p.x + lane + 64]);
            }
        }
        __syncthreads();   // protect cnt/sorted before next chunk
    }

    // Write out this bin's rows.
    int row0 = bin << BINSHIFT;
    #pragma unroll
    for (int rr = 0; rr < 4; ++rr) {
        int row = row0 + hw * 4 + rr;
        if (row < N) {
            float* o = out + (size_t)row * DFEAT;
            o[lane]      = acc[rr][0];
            o[lane + 32] = acc[rr][1];
            o[lane + 64] = acc[rr][2];
        }
    }
}

// Last-resort fallback (R1 baseline) if sizes/ws don't fit the main path.
__global__ void gcn_scatter_atomic_kernel(const int* __restrict__ rows, const int* __restrict__ cols,
                                          const float* __restrict__ vals, const float* __restrict__ embeds,
                                          float* __restrict__ out, int n_edges) {
    long long i = (long long)blockIdx.x * blockDim.x + threadIdx.x;
    long long total = (long long)n_edges * (DFEAT / 4);
    if (i >= total) return;
    int e = (int)(i / (DFEAT / 4));
    int q = (int)(i - (long long)e * (DFEAT / 4));
    int r = rows[e], c = cols[e];
    float v = vals[e];
    const float4* emb4 = reinterpret_cast<const float4*>(embeds + (long long)c * DFEAT);
    float4 x = emb4[q];
    float* o = out + (long long)r * DFEAT + q * 4;
    atomicAdd(o + 0, v * x.x);
    atomicAdd(o + 1, v * x.y);
    atomicAdd(o + 2, v * x.z);
    atomicAdd(o + 3, v * x.w);
}

extern "C" void kernel_launch(void* const* d_in, const int* in_sizes, int n_in,
                              void* d_out, int out_size, void* d_ws, size_t ws_size,
                              hipStream_t stream) {
    const int*   rows   = (const int*)d_in[0];
    const int*   cols   = (const int*)d_in[1];
    const float* vals   = (const float*)d_in[2];
    const float* embeds = (const float*)d_in[3];
    float*       out    = (float*)d_out;

    int E = in_sizes[0];
    int N = in_sizes[3] / DFEAT;

    int nbin  = (N + BINROWS - 1) >> BINSHIFT;        // 1563
    int B     = (E + EPB - 1) / EPB;                  // 196
    long long flatN = (long long)nbin * B;            // 306,348
    int SB    = (int)((flatN + SCT - 1) / SCT);       // 300

    // Workspace: matrix[flatN] | bsums[SB] | counter[1] | bucket[E] (int2)
    //            | ebf[N*96] (u16)
    size_t off_matrix  = 0;
    size_t off_bsums   = (off_matrix + (size_t)flatN * 4 + 15) & ~(size_t)15;
    size_t off_counter = (off_bsums + (size_t)SB * 4 + 15) & ~(size_t)15;
    size_t off_bucket  = (off_counter + 4 + 15) & ~(size_t)15;
    size_t off_ebf     = (off_bucket + (size_t)E * 8 + 63) & ~(size_t)63;
    size_t need        = off_ebf + (size_t)N * DFEAT * 2;

    bool ok = (N <= 65536) && (nbin <= MAXBIN) && (SB <= SCT) &&
              ((in_sizes[3] & 7) == 0) && (ws_size >= need);

    if (ok) {
        int*  matrix  = (int*)((char*)d_ws + off_matrix);
        int*  bsums   = (int*)((char*)d_ws + off_bsums);
        int*  counter = (int*)((char*)d_ws + off_counter);
        int2* bucket  = (int2*)((char*)d_ws + off_bucket);
        unsigned short* ebf = (unsigned short*)((char*)d_ws + off_ebf);

        int nOct = in_sizes[3] / 8;
        int cb   = (nOct + 511) / 512;   // compress blocks at 512 threads

        hist_bin_compress_kernel<<<B + cb, 512, 0, stream>>>(
            rows, matrix, E, B, nbin, embeds, ebf, nOct, counter);

        scan1024_dc_kernel<<<SB, SCT, 0, stream>>>(matrix, bsums, counter, (int)flatN, SB);

        scatter_bin_kernel<<<B, 512, 0, stream>>>(rows, cols, vals, matrix, bsums,
                                                  bucket, E, B, nbin);

        sortaccum_kernel<<<nbin, 256, 0, stream>>>(bucket, matrix, bsums, ebf, out,
                                                   E, B, nbin, N);
    } else {
        hipMemsetAsync(d_out, 0, (size_t)out_size * sizeof(float), stream);
        long long total = (long long)E * (DFEAT / 4);
        int block = 256;
        long long grid = (total + block - 1) / block;
        gcn_scatter_atomic_kernel<<<(int)grid, block, 0, stream>>>(rows, cols, vals, embeds, out, E);
    }
}

// Round 17
// 59.375 us; speedup vs baseline: 2.3012x; 2.3012x over previous
//
#include <hip/hip_runtime.h>

// GCN layer: out = scatter_add(rows, vals[:,None] * embeds[cols]) over COO.
// N=50000, E=800000, D=96 (fp32 in/out; indices int32 per harness).
//
// R13: fused sort+accumulate + premultiplied col*96: 65.2us.
// R14: EPB 1024 FAILED (uncoalesced (bin,block)-matrix traffic x4): 71.9us.
// R15: R13 + 512-thread hist/scatter blocks (TLP, zero extra traffic): 59.6us. BEST.
// R16: decoupled scan FAILED (136us): __threadfence() on gfx950 = L2
//      writeback/invalidate; 2 fences x 300 blocks x 16 waves ~ 85us.
//      Lesson: device-scope fences are cache-maintenance ops, keep them off
//      the per-block fast path.
// R17: exact R15 revert. Practical floor: sortaccum ~31us latency-bound
//      random gather (5 restructurings tried), build ~17us, gaps ~8us.

#define DFEAT    96
#define BINSHIFT 5
#define BINROWS  32            // rows per bin
#define MAXBIN   2048          // LDS hist/cursor capacity (8KB)
#define EPB      4096          // edges per hist/scatter block
#define SCT      1024          // scan width
#define CAP      1024          // edges per sortaccum chunk (8KB LDS)

__device__ inline unsigned bf16_rne(float x) {
    unsigned u = __float_as_uint(x);
    return (u + 0x7FFFu + ((u >> 16) & 1u)) >> 16;
}
__device__ inline float bf16_to_f32(unsigned short u) {
    return __uint_as_float((unsigned)u << 16);
}

// Blocks [0,B): LDS histogram of this block's EPB edges over nbin bins,
//   written to matrix[bin*B + block] (bin-major for the flat scan).
// Blocks [B,...): fp32 -> bf16 embeds compression (8 floats/thread, row-major).
// Launched with 512 threads (8 waves/block) for latency hiding.
__global__ void hist_bin_compress_kernel(const int* __restrict__ rows,
                                         int* __restrict__ matrix, int E, int B, int nbin,
                                         const float* __restrict__ embeds,
                                         unsigned short* __restrict__ ebf, int nOct) {
    __shared__ int cnt[MAXBIN];
    int b = blockIdx.x;
    if (b < B) {
        for (int k = threadIdx.x; k < nbin; k += blockDim.x) cnt[k] = 0;
        __syncthreads();
        int base = b * EPB;
        int lim  = min(base + EPB, E);
        for (int i = base + threadIdx.x; i < lim; i += blockDim.x)
            atomicAdd(&cnt[rows[i] >> BINSHIFT], 1);
        __syncthreads();
        for (int k = threadIdx.x; k < nbin; k += blockDim.x)
            matrix[(size_t)k * B + b] = cnt[k];
    } else {
        int j = (b - B) * blockDim.x + threadIdx.x;
        if (j < nOct) {
            const float4* src = reinterpret_cast<const float4*>(embeds) + (size_t)j * 2;
            float4 f0 = src[0];
            float4 f1 = src[1];
            uint4 o;
            o.x = bf16_rne(f0.x) | (bf16_rne(f0.y) << 16);
            o.y = bf16_rne(f0.z) | (bf16_rne(f0.w) << 16);
            o.z = bf16_rne(f1.x) | (bf16_rne(f1.y) << 16);
            o.w = bf16_rne(f1.z) | (bf16_rne(f1.w) << 16);
            reinterpret_cast<uint4*>(ebf)[j] = o;
        }
    }
}

// In-place per-block exclusive scan (one elem/thread, coalesced); block sums out.
// Result is partial — consumers add bsums[flatIdx >> 10] themselves.
__global__ void scan1024_kernel(int* __restrict__ data, int* __restrict__ bsums, int n) {
    __shared__ int s[SCT];
    int t = threadIdx.x;
    int i = blockIdx.x * SCT + t;
    int v = (i < n) ? data[i] : 0;
    s[t] = v;
    __syncthreads();
    for (int off = 1; off < SCT; off <<= 1) {
        int u = (t >= off) ? s[t - off] : 0;
        __syncthreads();
        s[t] += u;
        __syncthreads();
    }
    if (i < n) data[i] = s[t] - v;
    if (t == SCT - 1) bsums[blockIdx.x] = s[t];
}

// Single-block in-place exclusive scan of the block sums (nb <= SCT).
__global__ void scan_sums1024_kernel(int* __restrict__ bsums, int nb) {
    __shared__ int s[SCT];
    int t = threadIdx.x;
    int v = (t < nb) ? bsums[t] : 0;
    s[t] = v;
    __syncthreads();
    for (int off = 1; off < SCT; off <<= 1) {
        int u = (t >= off) ? s[t - off] : 0;
        __syncthreads();
        s[t] += u;
        __syncthreads();
    }
    if (t < nb) bsums[t] = s[t] - v;
}

__device__ inline int scanned_at(const int* __restrict__ matrixScan,
                                 const int* __restrict__ bsums, long long flatIdx) {
    return matrixScan[flatIdx] + bsums[flatIdx >> 10];
}

// Scatter edges to row-bin buckets. Cursor bases from the scanned matrix
// (+bsums fixup); within-block ranks via LDS atomics only.
// entry: (lrow<<16 | col, val) with lrow in [0,32), col < 65536.
// Launched with 512 threads (8 waves/block) for latency hiding.
__global__ void scatter_bin_kernel(const int* __restrict__ rows, const int* __restrict__ cols,
                                   const float* __restrict__ vals,
                                   const int* __restrict__ matrixScan,
                                   const int* __restrict__ bsums,
                                   int2* __restrict__ bucket, int E, int B, int nbin) {
    __shared__ int cur[MAXBIN];
    int b = blockIdx.x;
    for (int k = threadIdx.x; k < nbin; k += blockDim.x)
        cur[k] = scanned_at(matrixScan, bsums, (long long)k * B + b);
    __syncthreads();
    int base = b * EPB;
    int lim  = min(base + EPB, E);
    for (int i = base + threadIdx.x; i < lim; i += blockDim.x) {
        int r = rows[i];
        int bin = r >> BINSHIFT;
        int pos = atomicAdd(&cur[bin], 1);
        bucket[pos] = make_int2(((r & (BINROWS - 1)) << 16) | cols[i],
                                __float_as_int(vals[i]));
    }
}

// One 256-thread block per 32-row bin. Per 1024-edge chunk: edges -> registers
// (coalesced), LDS count over 32 row-counters, 32-wide LDS scan, cursor-scatter
// into sorted LDS (stores PREMULTIPLIED col*96 — lrow implicit in segments);
// then each half-wave accumulates its 4 rows from LDS (broadcast reads) with
// register accumulators persisting across chunks. Single feature pass.
__global__ void sortaccum_kernel(const int2* __restrict__ bucket,
                                 const int* __restrict__ matrixScan,
                                 const int* __restrict__ bsums,
                                 const unsigned short* __restrict__ ebf,
                                 float* __restrict__ out, int E, int B, int nbin, int N) {
    __shared__ int2 sorted[CAP];     // 8 KB
    __shared__ int cnt[BINROWS];
    __shared__ int segs[BINROWS];
    __shared__ int cur[BINROWS];
    __shared__ int s32[BINROWS];

    int bin = blockIdx.x;
    int t = threadIdx.x;
    int hw = t >> 5;                 // 8 half-waves
    int lane = t & 31;

    int start = scanned_at(matrixScan, bsums, (long long)bin * B);
    int end   = (bin + 1 < nbin) ? scanned_at(matrixScan, bsums, (long long)(bin + 1) * B) : E;

    float acc[4][3];
    #pragma unroll
    for (int rr = 0; rr < 4; ++rr) { acc[rr][0] = 0.f; acc[rr][1] = 0.f; acc[rr][2] = 0.f; }

    for (int cs = start; cs < end; cs += CAP) {
        int m = min(CAP, end - cs);

        if (t < BINROWS) cnt[t] = 0;
        __syncthreads();

        // Load chunk edges into registers + LDS count.
        int2 ee[4];
        #pragma unroll
        for (int k = 0; k < 4; ++k) {
            int j = t + k * 256;
            if (j < m) {
                ee[k] = bucket[cs + j];
                atomicAdd(&cnt[ee[k].x >> 16], 1);
            }
        }
        __syncthreads();

        // Exclusive scan of the 32 counters.
        if (t < BINROWS) s32[t] = cnt[t];
        __syncthreads();
        for (int off = 1; off < BINROWS; off <<= 1) {
            int u = (t < BINROWS && t >= off) ? s32[t - off] : 0;
            __syncthreads();
            if (t < BINROWS) s32[t] += u;
            __syncthreads();
        }
        if (t < BINROWS) {
            int ex = s32[t] - cnt[t];
            segs[t] = ex;
            cur[t]  = ex;
        }
        __syncthreads();

        // Cursor-scatter into sorted LDS; store premultiplied row offset col*96.
        #pragma unroll
        for (int k = 0; k < 4; ++k) {
            int j = t + k * 256;
            if (j < m) {
                int pos = atomicAdd(&cur[ee[k].x >> 16], 1);
                sorted[pos] = make_int2((ee[k].x & 0xFFFF) * DFEAT, ee[k].y);
            }
        }
        __syncthreads();

        // Accumulate: half-wave hw owns rows hw*4 .. hw*4+3.
        #pragma unroll
        for (int rr = 0; rr < 4; ++rr) {
            int r = hw * 4 + rr;
            int j  = segs[r];
            int je = segs[r] + cnt[r];
            for (; j + 4 <= je; j += 4) {
                int2 p0 = sorted[j];
                int2 p1 = sorted[j + 1];
                int2 p2 = sorted[j + 2];
                int2 p3 = sorted[j + 3];
                float v0 = __int_as_float(p0.y), v1 = __int_as_float(p1.y);
                float v2 = __int_as_float(p2.y), v3 = __int_as_float(p3.y);
                float x0 = bf16_to_f32(ebf[p0.x + lane]);
                float y0 = bf16_to_f32(ebf[p0.x + lane + 32]);
                float z0 = bf16_to_f32(ebf[p0.x + lane + 64]);
                float x1 = bf16_to_f32(ebf[p1.x + lane]);
                float y1 = bf16_to_f32(ebf[p1.x + lane + 32]);
                float z1 = bf16_to_f32(ebf[p1.x + lane + 64]);
                float x2 = bf16_to_f32(ebf[p2.x + lane]);
                float y2 = bf16_to_f32(ebf[p2.x + lane + 32]);
                float z2 = bf16_to_f32(ebf[p2.x + lane + 64]);
                float x3 = bf16_to_f32(ebf[p3.x + lane]);
                float y3 = bf16_to_f32(ebf[p3.x + lane + 32]);
                float z3 = bf16_to_f32(ebf[p3.x + lane + 64]);
                acc[rr][0] += v0 * x0 + v1 * x1;
                acc[rr][1] += v0 * y0 + v1 * y1;
                acc[rr][2] += v0 * z0 + v1 * z1;
                acc[rr][0] += v2 * x2 + v3 * x3;
                acc[rr][1] += v2 * y2 + v3 * y3;
                acc[rr][2] += v2 * z2 + v3 * z3;
            }
            for (; j < je; ++j) {
                int2 p = sorted[j];
                float v = __int_as_float(p.y);
                acc[rr][0] += v * bf16_to_f32(ebf[p.x + lane]);
                acc[rr][1] += v * bf16_to_f32(ebf[p.x + lane + 32]);
                acc[rr][2] += v * bf16_to_f32(ebf[p.x + lane + 64]);
            }
        }
        __syncthreads();   // protect cnt/sorted before next chunk
    }

    // Write out this bin's rows.
    int row0 = bin << BINSHIFT;
    #pragma unroll
    for (int rr = 0; rr < 4; ++rr) {
        int row = row0 + hw * 4 + rr;
        if (row < N) {
            float* o = out + (size_t)row * DFEAT;
            o[lane]      = acc[rr][0];
            o[lane + 32] = acc[rr][1];
            o[lane + 64] = acc[rr][2];
        }
    }
}

// Last-resort fallback (R1 baseline) if sizes/ws don't fit the main path.
__global__ void gcn_scatter_atomic_kernel(const int* __restrict__ rows, const int* __restrict__ cols,
                                          const float* __restrict__ vals, const float* __restrict__ embeds,
                                          float* __restrict__ out, int n_edges) {
    long long i = (long long)blockIdx.x * blockDim.x + threadIdx.x;
    long long total = (long long)n_edges * (DFEAT / 4);
    if (i >= total) return;
    int e = (int)(i / (DFEAT / 4));
    int q = (int)(i - (long long)e * (DFEAT / 4));
    int r = rows[e], c = cols[e];
    float v = vals[e];
    const float4* emb4 = reinterpret_cast<const float4*>(embeds + (long long)c * DFEAT);
    float4 x = emb4[q];
    float* o = out + (long long)r * DFEAT + q * 4;
    atomicAdd(o + 0, v * x.x);
    atomicAdd(o + 1, v * x.y);
    atomicAdd(o + 2, v * x.z);
    atomicAdd(o + 3, v * x.w);
}

extern "C" void kernel_launch(void* const* d_in, const int* in_sizes, int n_in,
                              void* d_out, int out_size, void* d_ws, size_t ws_size,
                              hipStream_t stream) {
    const int*   rows   = (const int*)d_in[0];
    const int*   cols   = (const int*)d_in[1];
    const float* vals   = (const float*)d_in[2];
    const float* embeds = (const float*)d_in[3];
    float*       out    = (float*)d_out;

    int E = in_sizes[0];
    int N = in_sizes[3] / DFEAT;

    int nbin  = (N + BINROWS - 1) >> BINSHIFT;        // 1563
    int B     = (E + EPB - 1) / EPB;                  // 196
    long long flatN = (long long)nbin * B;            // 306,348
    int SB    = (int)((flatN + SCT - 1) / SCT);       // 300

    // Workspace: matrix[flatN] | bsums[SB] | bucket[E] (int2) | ebf[N*96] (u16)
    size_t off_matrix = 0;
    size_t off_bsums  = (off_matrix + (size_t)flatN * 4 + 15) & ~(size_t)15;
    size_t off_bucket = (off_bsums + (size_t)SB * 4 + 15) & ~(size_t)15;
    size_t off_ebf    = (off_bucket + (size_t)E * 8 + 63) & ~(size_t)63;
    size_t need       = off_ebf + (size_t)N * DFEAT * 2;

    bool ok = (N <= 65536) && (nbin <= MAXBIN) && (SB <= SCT) &&
              ((in_sizes[3] & 7) == 0) && (ws_size >= need);

    if (ok) {
        int*  matrix = (int*)((char*)d_ws + off_matrix);
        int*  bsums  = (int*)((char*)d_ws + off_bsums);
        int2* bucket = (int2*)((char*)d_ws + off_bucket);
        unsigned short* ebf = (unsigned short*)((char*)d_ws + off_ebf);

        int nOct = in_sizes[3] / 8;
        int cb   = (nOct + 511) / 512;   // compress blocks at 512 threads

        hist_bin_compress_kernel<<<B + cb, 512, 0, stream>>>(
            rows, matrix, E, B, nbin, embeds, ebf, nOct);

        scan1024_kernel<<<SB, SCT, 0, stream>>>(matrix, bsums, (int)flatN);
        scan_sums1024_kernel<<<1, SCT, 0, stream>>>(bsums, SB);

        scatter_bin_kernel<<<B, 512, 0, stream>>>(rows, cols, vals, matrix, bsums,
                                                  bucket, E, B, nbin);

        sortaccum_kernel<<<nbin, 256, 0, stream>>>(bucket, matrix, bsums, ebf, out,
                                                   E, B, nbin, N);
    } else {
        hipMemsetAsync(d_out, 0, (size_t)out_size * sizeof(float), stream);
        long long total = (long long)E * (DFEAT / 4);
        int block = 256;
        long long grid = (total + block - 1) / block;
        gcn_scatter_atomic_kernel<<<(int)grid, block, 0, stream>>>(rows, cols, vals, embeds, out, E);
    }
}